// Round 12
// baseline (146.853 us; speedup 1.0000x reference)
//
#include <hip/hip_runtime.h>

typedef _Float16 f16;
typedef _Float16 f16x2 __attribute__((ext_vector_type(2)));
typedef _Float16 f16x8 __attribute__((ext_vector_type(8)));
typedef float    f32x4 __attribute__((ext_vector_type(4)));

#define KW 31
#define R  15
#define NP 32
#define HH 512
#define WW 512
#define NB 4

#define TW 32            // output tile width (px)
#define TH 32            // output tile height
#define EXT_X 62         // TW + 30 data cols
#define SX 80            // tile row stride in f16 (mult of 8 -> 16B-aligned b128 frags)
#define EXT_Y 63         // TH + 30 data rows + 1 pad row (row 62, zeroed)
#define GH_S 81          // gTh row stride (f16): [15+d], d in [-15,65]
#define GYF_S 36         // gTyF row stride (f32): 144 B, 16B-aligned rows

__global__ __launch_bounds__(256, 1) void defocus_kernel(
    const float* __restrict__ sharp, const float* __restrict__ coc_map,
    float* __restrict__ out)
{
    __shared__ __align__(16) f16 tile[3][EXT_Y][SX];   // 30.2 KB
    __shared__ __align__(16) f16 gTh[NP][GH_S];        // band-matrix source: [plane][15 + d]
    __shared__ __align__(16) float gTyF[NP][GYF_S];    // y-weights f32: [plane][dy], zero-padded
    __shared__ unsigned char pl8[TH][TW];
    __shared__ float bnd[KW];

    const int tid = threadIdx.x;
    const int bx = blockIdx.x, by = blockIdx.y, bb = blockIdx.z;

    // ---- phase 1: per-plane Gaussian weights (zero-padded) + boundaries ----
    if (tid < NP) {
        const int p = tid;
        for (int i = 0; i < GH_S; ++i) gTh[p][i] = (f16)0.0f;
        for (int i = 0; i < GYF_S; ++i) gTyF[p][i] = 0.0f;
        const double step = 50.0 / 31.0;
        const float pv = (p == 31) ? 50.0f : (float)((double)p * step);
        if (pv < 0.5f) {
            gTh[p][15 + R] = (f16)1.0f;
            gTyF[p][R]     = 1.0f;
        } else {
            const double coc   = (double)pv;
            const double sigma = coc / 2.355;
            int k = (int)(2.0 * coc + 1.0);
            if ((k & 1) == 0) k += 1;
            if (k > KW) k = KW;
            const int half = k >> 1;
            float s = 0.0f;
            for (int j = 0; j < k; ++j) {
                double c = (double)(j - half);
                s += (float)exp(-(c * c) / (2.0 * sigma * sigma));
            }
            for (int j = 0; j < k; ++j) {
                double c = (double)(j - half);
                const float w = (float)exp(-(c * c) / (2.0 * sigma * sigma)) / s;
                const int d = R - half + j;           // tap index 0..30
                gTh[p][15 + d] = (f16)w;
                gTyF[p][d]     = w;
            }
        }
    }
    if (tid < KW) {
        const double step = 50.0 / 31.0;
        const float pa = (float)((double)tid * step);
        const float pb = (tid == 30) ? 50.0f : (float)((double)(tid + 1) * step);
        bnd[tid] = (pa + pb) * 0.5f;
    }
    __syncthreads();

    // ---- phase 2a: per-pixel plane selection (exact: count coc > bnd[k]) ----
    {
        const int row = tid >> 3;
        const int x4  = (tid & 7) * 4;
        const float4 c4 = *(const float4*)&coc_map[((size_t)bb * HH + by * TH + row) * WW + bx * TW + x4];
        const float cv[4] = {c4.x, c4.y, c4.z, c4.w};
        int pp[4] = {0, 0, 0, 0};
        #pragma unroll
        for (int k = 0; k < KW; ++k) {
            const float b = bnd[k];
            pp[0] += (cv[0] > b) ? 1 : 0;
            pp[1] += (cv[1] > b) ? 1 : 0;
            pp[2] += (cv[2] > b) ? 1 : 0;
            pp[3] += (cv[3] > b) ? 1 : 0;
        }
        *(uchar4*)&pl8[row][x4] = make_uchar4((unsigned char)pp[0], (unsigned char)pp[1],
                                              (unsigned char)pp[2], (unsigned char)pp[3]);
    }

    // ---- phase 2b: stage tile (+halo) as f16, zero all padding ----
    for (int idx = tid; idx < 3 * EXT_Y * (SX / 2); idx += 256) {
        const int dw = idx % (SX / 2);
        const int rr = (idx / (SX / 2)) % EXT_Y;
        const int ch = idx / ((SX / 2) * EXT_Y);
        const int gy  = by * TH - R + rr;
        const int gxa = bx * TW - R + 2 * dw;
        float va = 0.0f, vb = 0.0f;
        if (rr < 62 && (unsigned)gy < HH) {
            const float* src = &sharp[(((size_t)bb * 3 + ch) * HH + gy) * WW];
            if (2 * dw     < EXT_X && (unsigned)gxa       < WW) va = src[gxa];
            if (2 * dw + 1 < EXT_X && (unsigned)(gxa + 1) < WW) vb = src[gxa + 1];
        }
        f16x2 h; h.x = (f16)va; h.y = (f16)vb;
        *(f16x2*)&tile[ch][rr][2 * dw] = h;
    }
    __syncthreads();

    // ---- phase 3: per-wave GEMM, SWAPPED operands: D[dy][px] = data · weights ----
    const int lid = tid & 63, wv = tid >> 6;
    const int c = lid & 15, q = lid >> 4;      // c: MFMA 16-lane dim, q: quad

    for (int t = wv; t < 64; t += 4) {          // 64 tasks: 2 x-segs x 32 rows
        const int sx = t >> 5, r = t & 31;
        const int xs = sx * 16;

        // weight B-fragment: B[k=q*8+j][n=c] = g_{plane(px c)}[k - c] (tap idx k-c in [0,30])
        const int pm = pl8[r][xs + c];          // this lane's pixel's plane
        f16x8 b0, b1;
        #pragma unroll
        for (int j = 0; j < 8; ++j) {
            b0[j] = gTh[pm][q * 8 + j      - c + 15];
            b1[j] = gTh[pm][q * 8 + j + 32 - c + 15];
        }

        // y-weights for the dy rows this lane owns in D (dy = 4q+i + 16nt)
        const f32x4 wyA = *(const f32x4*)&gTyF[pm][4 * q];
        const f32x4 wyB = *(const f32x4*)&gTyF[pm][16 + 4 * q];

        float o[3];
        #pragma unroll
        for (int ch = 0; ch < 3; ++ch) {
            float s = 0.0f;
            #pragma unroll
            for (int nt = 0; nt < 2; ++nt) {
                // data A-fragment: A[m=c (dy row)][k=q*8+j] = tile[r+16nt+c][xs+k]
                const f16* ap = &tile[ch][r + nt * 16 + c][xs + q * 8];
                const f16x8 a0 = *(const f16x8*)ap;
                const f16x8 a1 = *(const f16x8*)(ap + 32);
                f32x4 acc = {0.f, 0.f, 0.f, 0.f};
                acc = __builtin_amdgcn_mfma_f32_16x16x32_f16(a0, b0, acc, 0, 0, 0);
                acc = __builtin_amdgcn_mfma_f32_16x16x32_f16(a1, b1, acc, 0, 0, 0);
                // lane holds S^T[dy=4q+i+16nt][px=c] in acc[i]; weight by wy now
                const f32x4 wy = nt ? wyB : wyA;
                #pragma unroll
                for (int i = 0; i < 4; ++i) s = fmaf(wy[i], acc[i], s);
            }
            o[ch] = s;
        }

        // cross-quad sum: lanes {c, c+16, c+32, c+48} hold the 4 dy-partials
        #pragma unroll
        for (int ch = 0; ch < 3; ++ch) {
            o[ch] += __shfl_xor(o[ch], 16, 64);
            o[ch] += __shfl_xor(o[ch], 32, 64);
        }

        if (q == 0) {
            const int ox = bx * TW + xs + c;
            const int oy = by * TH + r;
            #pragma unroll
            for (int ch = 0; ch < 3; ++ch)
                out[(((size_t)bb * 3 + ch) * HH + oy) * WW + ox] = o[ch];
        }
    }
}

extern "C" void kernel_launch(void* const* d_in, const int* in_sizes, int n_in,
                              void* d_out, int out_size, void* d_ws, size_t ws_size,
                              hipStream_t stream) {
    const float* sharp = (const float*)d_in[0];
    const float* coc   = (const float*)d_in[1];
    float* outp        = (float*)d_out;
    dim3 grid(WW / TW, HH / TH, NB);
    defocus_kernel<<<grid, dim3(256), 0, stream>>>(sharp, coc, outp);
}

// Round 13
// 119.647 us; speedup vs baseline: 1.2274x; 1.2274x over previous
//
#include <hip/hip_runtime.h>

typedef _Float16 f16;
typedef _Float16 f16x2 __attribute__((ext_vector_type(2)));
typedef _Float16 f16x4 __attribute__((ext_vector_type(4)));
typedef _Float16 f16x8 __attribute__((ext_vector_type(8)));
typedef float    f32x4 __attribute__((ext_vector_type(4)));

#define KW 31
#define R  15
#define NP 32
#define HH 512
#define WW 512
#define NB 4

#define TW 32            // output tile width (px)
#define TH 32            // output tile height
#define EXT_X 62         // TW + 30 data cols
#define SX 80            // tile row stride in f16 (mult of 8 -> 16B-aligned b128 frags)
#define EXT_Y 63         // TH + 30 data rows + 1 pad row (row 62, zeroed)
#define GH_S 81          // gTh row stride (f16): [15+d], d in [-15,65]
#define GY_S 36          // gTy row stride (f16): 72 B rows, 8B-aligned subreads

// LDS budget: tile 30240 + gTh 5184 + gTy 2304 + pl8 1024 + bnd 124 ≈ 38.9 KB
// -> 4 blocks/CU (R12's f32 gTy pushed past 40960 -> 3 blocks/CU -> 94 µs).
__global__ __launch_bounds__(256, 1) void defocus_kernel(
    const float* __restrict__ sharp, const float* __restrict__ coc_map,
    float* __restrict__ out)
{
    __shared__ __align__(16) f16 tile[3][EXT_Y][SX];
    __shared__ __align__(16) f16 gTh[NP][GH_S];        // band-matrix source: [plane][15 + d]
    __shared__ __align__(16) f16 gTy[NP][GY_S];        // y-weights f16: [plane][dy], zero-padded
    __shared__ unsigned char pl8[TH][TW];
    __shared__ float bnd[KW];

    const int tid = threadIdx.x;
    const int bx = blockIdx.x, by = blockIdx.y, bb = blockIdx.z;

    // ---- phase 1: per-plane Gaussian weights (zero-padded) + boundaries ----
    if (tid < NP) {
        const int p = tid;
        for (int i = 0; i < GH_S; ++i) gTh[p][i] = (f16)0.0f;
        for (int i = 0; i < GY_S; ++i) gTy[p][i] = (f16)0.0f;
        const double step = 50.0 / 31.0;
        const float pv = (p == 31) ? 50.0f : (float)((double)p * step);
        if (pv < 0.5f) {
            gTh[p][15 + R] = (f16)1.0f;
            gTy[p][R]      = (f16)1.0f;
        } else {
            const double coc   = (double)pv;
            const double sigma = coc / 2.355;
            int k = (int)(2.0 * coc + 1.0);
            if ((k & 1) == 0) k += 1;
            if (k > KW) k = KW;
            const int half = k >> 1;
            float s = 0.0f;
            for (int j = 0; j < k; ++j) {
                double c = (double)(j - half);
                s += (float)exp(-(c * c) / (2.0 * sigma * sigma));
            }
            for (int j = 0; j < k; ++j) {
                double c = (double)(j - half);
                const float w = (float)exp(-(c * c) / (2.0 * sigma * sigma)) / s;
                const int d = R - half + j;           // tap index 0..30
                gTh[p][15 + d] = (f16)w;
                gTy[p][d]      = (f16)w;
            }
        }
    }
    if (tid < KW) {
        const double step = 50.0 / 31.0;
        const float pa = (float)((double)tid * step);
        const float pb = (tid == 30) ? 50.0f : (float)((double)(tid + 1) * step);
        bnd[tid] = (pa + pb) * 0.5f;
    }
    __syncthreads();

    // ---- phase 2a: per-pixel plane selection (exact: count coc > bnd[k]) ----
    {
        const int row = tid >> 3;
        const int x4  = (tid & 7) * 4;
        const float4 c4 = *(const float4*)&coc_map[((size_t)bb * HH + by * TH + row) * WW + bx * TW + x4];
        const float cv[4] = {c4.x, c4.y, c4.z, c4.w};
        int pp[4] = {0, 0, 0, 0};
        #pragma unroll
        for (int k = 0; k < KW; ++k) {
            const float b = bnd[k];
            pp[0] += (cv[0] > b) ? 1 : 0;
            pp[1] += (cv[1] > b) ? 1 : 0;
            pp[2] += (cv[2] > b) ? 1 : 0;
            pp[3] += (cv[3] > b) ? 1 : 0;
        }
        *(uchar4*)&pl8[row][x4] = make_uchar4((unsigned char)pp[0], (unsigned char)pp[1],
                                              (unsigned char)pp[2], (unsigned char)pp[3]);
    }

    // ---- phase 2b: stage tile (+halo) as f16, zero all padding ----
    for (int idx = tid; idx < 3 * EXT_Y * (SX / 2); idx += 256) {
        const int dw = idx % (SX / 2);
        const int rr = (idx / (SX / 2)) % EXT_Y;
        const int ch = idx / ((SX / 2) * EXT_Y);
        const int gy  = by * TH - R + rr;
        const int gxa = bx * TW - R + 2 * dw;
        float va = 0.0f, vb = 0.0f;
        if (rr < 62 && (unsigned)gy < HH) {
            const float* src = &sharp[(((size_t)bb * 3 + ch) * HH + gy) * WW];
            if (2 * dw     < EXT_X && (unsigned)gxa       < WW) va = src[gxa];
            if (2 * dw + 1 < EXT_X && (unsigned)(gxa + 1) < WW) vb = src[gxa + 1];
        }
        f16x2 h; h.x = (f16)va; h.y = (f16)vb;
        *(f16x2*)&tile[ch][rr][2 * dw] = h;
    }
    __syncthreads();

    // ---- phase 3: per-wave GEMM, D[dy][px] = data · weights (lane-local epilogue) ----
    const int lid = tid & 63, wv = tid >> 6;
    const int c = lid & 15, q = lid >> 4;      // c: MFMA 16-lane dim, q: quad

    #pragma unroll 2
    for (int t = wv; t < 64; t += 4) {          // 64 tasks: 2 x-segs x 32 rows
        const int sx = t >> 5, r = t & 31;
        const int xs = sx * 16;

        // weight B-fragment: B[k=q*8+j][n=c] = g_{plane(px c)}[k - c]
        const int pm = pl8[r][xs + c];
        f16x8 b0, b1;
        #pragma unroll
        for (int j = 0; j < 8; ++j) {
            b0[j] = gTh[pm][q * 8 + j      - c + 15];
            b1[j] = gTh[pm][q * 8 + j + 32 - c + 15];
        }

        // y-weights for the dy rows this lane owns (dy = 4q+i+16nt), f16, 8B-aligned
        const f16x4 wyA = *(const f16x4*)&gTy[pm][4 * q];
        const f16x4 wyB = *(const f16x4*)&gTy[pm][16 + 4 * q];

        float o[3];
        #pragma unroll
        for (int ch = 0; ch < 3; ++ch) {
            float s = 0.0f;
            #pragma unroll
            for (int nt = 0; nt < 2; ++nt) {
                // data A-fragment: A[m=c (dy row)][k=q*8+j] = tile[r+16nt+c][xs+k]
                const f16* ap = &tile[ch][r + nt * 16 + c][xs + q * 8];
                const f16x8 a0 = *(const f16x8*)ap;
                const f16x8 a1 = *(const f16x8*)(ap + 32);
                f32x4 acc = {0.f, 0.f, 0.f, 0.f};
                acc = __builtin_amdgcn_mfma_f32_16x16x32_f16(a0, b0, acc, 0, 0, 0);
                acc = __builtin_amdgcn_mfma_f32_16x16x32_f16(a1, b1, acc, 0, 0, 0);
                const f16x4 wy = nt ? wyB : wyA;
                #pragma unroll
                for (int i = 0; i < 4; ++i) s = fmaf((float)wy[i], acc[i], s);
            }
            o[ch] = s;
        }

        // cross-quad sum: lanes {c, c+16, c+32, c+48} hold the 4 dy-partials
        #pragma unroll
        for (int ch = 0; ch < 3; ++ch) {
            o[ch] += __shfl_xor(o[ch], 16, 64);
            o[ch] += __shfl_xor(o[ch], 32, 64);
        }

        if (q == 0) {
            const int ox = bx * TW + xs + c;
            const int oy = by * TH + r;
            #pragma unroll
            for (int ch = 0; ch < 3; ++ch)
                out[(((size_t)bb * 3 + ch) * HH + oy) * WW + ox] = o[ch];
        }
    }
}

extern "C" void kernel_launch(void* const* d_in, const int* in_sizes, int n_in,
                              void* d_out, int out_size, void* d_ws, size_t ws_size,
                              hipStream_t stream) {
    const float* sharp = (const float*)d_in[0];
    const float* coc   = (const float*)d_in[1];
    float* outp        = (float*)d_out;
    dim3 grid(WW / TW, HH / TH, NB);
    defocus_kernel<<<grid, dim3(256), 0, stream>>>(sharp, coc, outp);
}

// Round 15
// 116.040 us; speedup vs baseline: 1.2655x; 1.0311x over previous
//
#include <hip/hip_runtime.h>

typedef _Float16 f16;
typedef _Float16 f16x2 __attribute__((ext_vector_type(2)));
typedef _Float16 f16x4 __attribute__((ext_vector_type(4)));
typedef _Float16 f16x8 __attribute__((ext_vector_type(8)));
typedef float    f32x4 __attribute__((ext_vector_type(4)));

#define KW 31
#define R  15
#define NP 32
#define HH 512
#define WW 512
#define NB 4

#define TW 32            // output tile width (px)
#define TH 32            // output tile height
#define EXT_X 62         // TW + 30 data cols (cols 62..79 zeroed)
#define SX 80            // tile row stride in f16 (mult of 8 -> 16B-aligned b128 frags)
#define EXT_Y 63         // TH + 30 data rows + 1 pad row (row 62, zeroed)
#define GH_S 96          // gTh row stride (f16): idx = 32 + tap, taps 0..30, rest zero
#define GB   32          // gTh storage base; lookup idx = GB + k - c - 16*seg, always in [1,95]
#define GY_S 36          // gTy row stride (f16): 72 B rows, 8B-aligned subreads

// LDS: tile 30240 + gTh 6144 + gTy 2304 + pl8 1024 + bnd 124 = 39836 B ≤ 40960
// -> 4 blocks/CU (hard requirement; R12's cliff at 41472 cost 40%).
__global__ __launch_bounds__(256, 1) void defocus_kernel(
    const float* __restrict__ sharp, const float* __restrict__ coc_map,
    float* __restrict__ out)
{
    __shared__ __align__(16) f16 tile[3][EXT_Y][SX];
    __shared__ __align__(16) f16 gTh[NP][GH_S];        // [plane][GB + tap]
    __shared__ __align__(16) f16 gTy[NP][GY_S];        // [plane][dy], zero-padded
    __shared__ unsigned char pl8[TH][TW];
    __shared__ float bnd[KW];

    const int tid = threadIdx.x;
    const int bx = blockIdx.x, by = blockIdx.y, bb = blockIdx.z;

    // ---- phase 1: per-plane Gaussian weights (zero-padded) + boundaries ----
    if (tid < NP) {
        const int p = tid;
        for (int i = 0; i < GH_S; ++i) gTh[p][i] = (f16)0.0f;
        for (int i = 0; i < GY_S; ++i) gTy[p][i] = (f16)0.0f;
        const double step = 50.0 / 31.0;
        const float pv = (p == 31) ? 50.0f : (float)((double)p * step);
        if (pv < 0.5f) {
            gTh[p][GB + R] = (f16)1.0f;
            gTy[p][R]      = (f16)1.0f;
        } else {
            const double coc   = (double)pv;
            const double sigma = coc / 2.355;
            int k = (int)(2.0 * coc + 1.0);
            if ((k & 1) == 0) k += 1;
            if (k > KW) k = KW;
            const int half = k >> 1;
            float s = 0.0f;
            for (int j = 0; j < k; ++j) {
                double c = (double)(j - half);
                s += (float)exp(-(c * c) / (2.0 * sigma * sigma));
            }
            for (int j = 0; j < k; ++j) {
                double c = (double)(j - half);
                const float w = (float)exp(-(c * c) / (2.0 * sigma * sigma)) / s;
                const int d = R - half + j;           // tap index 0..30
                gTh[p][GB + d] = (f16)w;
                gTy[p][d]      = (f16)w;
            }
        }
    }
    if (tid < KW) {
        const double step = 50.0 / 31.0;
        const float pa = (float)((double)tid * step);
        const float pb = (tid == 30) ? 50.0f : (float)((double)(tid + 1) * step);
        bnd[tid] = (pa + pb) * 0.5f;
    }
    __syncthreads();

    // ---- phase 2a: per-pixel plane selection (exact: count coc > bnd[k]) ----
    {
        const int row = tid >> 3;
        const int x4  = (tid & 7) * 4;
        const float4 c4 = *(const float4*)&coc_map[((size_t)bb * HH + by * TH + row) * WW + bx * TW + x4];
        const float cv[4] = {c4.x, c4.y, c4.z, c4.w};
        int pp[4] = {0, 0, 0, 0};
        #pragma unroll
        for (int k = 0; k < KW; ++k) {
            const float b = bnd[k];
            pp[0] += (cv[0] > b) ? 1 : 0;
            pp[1] += (cv[1] > b) ? 1 : 0;
            pp[2] += (cv[2] > b) ? 1 : 0;
            pp[3] += (cv[3] > b) ? 1 : 0;
        }
        *(uchar4*)&pl8[row][x4] = make_uchar4((unsigned char)pp[0], (unsigned char)pp[1],
                                              (unsigned char)pp[2], (unsigned char)pp[3]);
    }

    // ---- phase 2b: stage tile (+halo) as f16, zero all padding ----
    for (int idx = tid; idx < 3 * EXT_Y * (SX / 2); idx += 256) {
        const int dw = idx % (SX / 2);
        const int rr = (idx / (SX / 2)) % EXT_Y;
        const int ch = idx / ((SX / 2) * EXT_Y);
        const int gy  = by * TH - R + rr;
        const int gxa = bx * TW - R + 2 * dw;
        float va = 0.0f, vb = 0.0f;
        if (rr < 62 && (unsigned)gy < HH) {
            const float* src = &sharp[(((size_t)bb * 3 + ch) * HH + gy) * WW];
            if (2 * dw     < EXT_X && (unsigned)gxa       < WW) va = src[gxa];
            if (2 * dw + 1 < EXT_X && (unsigned)(gxa + 1) < WW) vb = src[gxa + 1];
        }
        f16x2 h; h.x = (f16)va; h.y = (f16)vb;
        *(f16x2*)&tile[ch][rr][2 * dw] = h;
    }
    __syncthreads();

    // ---- phase 3: merged-segment GEMM. One task = one row r, all 32 px. ----
    // Shared K=64 window (tile cols 0..63). Output px (seg s, lane c) is tile
    // col 16s+c+15; tap d = k - c - 16s; lookup gTh[GB + k - c - 16s].
    const int lid = tid & 63, wv = tid >> 6;
    const int c = lid & 15, q = lid >> 4;      // c: MFMA 16-lane dim, q: quad

    #pragma unroll 2
    for (int r = wv; r < TH; r += 4) {          // 32 tasks: one per row
        // planes for this lane's two pixels (seg0: px c, seg1: px 16+c)
        const int pm0 = pl8[r][c];
        const int pm1 = pl8[r][16 + c];

        // weight B-frags: k = 8q + j + 32*chunk
        f16x8 bfr[2][2];
        #pragma unroll
        for (int j = 0; j < 8; ++j) {
            const int base = GB + 8 * q + j - c;       // seg0, chunk0
            bfr[0][0][j] = gTh[pm0][base];             // idx in [17,55]
            bfr[0][1][j] = gTh[pm0][base + 32];        // idx in [49,87]
            bfr[1][0][j] = gTh[pm1][base - 16];        // idx in [1,39]
            bfr[1][1][j] = gTh[pm1][base + 16];        // idx in [33,71]
        }

        // y-weights for the dy rows this lane owns (dy = 4q+i+16nt)
        const f16x4 wy0A = *(const f16x4*)&gTy[pm0][4 * q];
        const f16x4 wy0B = *(const f16x4*)&gTy[pm0][16 + 4 * q];
        const f16x4 wy1A = *(const f16x4*)&gTy[pm1][4 * q];
        const f16x4 wy1B = *(const f16x4*)&gTy[pm1][16 + 4 * q];

        float o[2][3];
        #pragma unroll
        for (int ch = 0; ch < 3; ++ch) {
            float s0 = 0.0f, s1 = 0.0f;
            #pragma unroll
            for (int nt = 0; nt < 2; ++nt) {
                // shared data A-frag: A[m=c (dy row)][k=8q+j(+32)] = tile[r+16nt+c][k]
                const f16* ap = &tile[ch][r + nt * 16 + c][q * 8];
                const f16x8 a0 = *(const f16x8*)ap;
                const f16x8 a1 = *(const f16x8*)(ap + 32);
                f32x4 acc0 = {0.f, 0.f, 0.f, 0.f};
                acc0 = __builtin_amdgcn_mfma_f32_16x16x32_f16(a0, bfr[0][0], acc0, 0, 0, 0);
                acc0 = __builtin_amdgcn_mfma_f32_16x16x32_f16(a1, bfr[0][1], acc0, 0, 0, 0);
                f32x4 acc1 = {0.f, 0.f, 0.f, 0.f};
                acc1 = __builtin_amdgcn_mfma_f32_16x16x32_f16(a0, bfr[1][0], acc1, 0, 0, 0);
                acc1 = __builtin_amdgcn_mfma_f32_16x16x32_f16(a1, bfr[1][1], acc1, 0, 0, 0);
                const f16x4 w0 = nt ? wy0B : wy0A;
                const f16x4 w1 = nt ? wy1B : wy1A;
                #pragma unroll
                for (int i = 0; i < 4; ++i) {
                    s0 = fmaf((float)w0[i], acc0[i], s0);
                    s1 = fmaf((float)w1[i], acc1[i], s1);
                }
            }
            o[0][ch] = s0;
            o[1][ch] = s1;
        }

        // cross-quad sum: lanes {c, c+16, c+32, c+48} hold the 4 dy-partials
        #pragma unroll
        for (int sg = 0; sg < 2; ++sg)
            #pragma unroll
            for (int ch = 0; ch < 3; ++ch) {
                o[sg][ch] += __shfl_xor(o[sg][ch], 16, 64);
                o[sg][ch] += __shfl_xor(o[sg][ch], 32, 64);
            }

        if (q == 0) {
            const int oy = by * TH + r;
            #pragma unroll
            for (int sg = 0; sg < 2; ++sg) {
                const int ox = bx * TW + 16 * sg + c;
                #pragma unroll
                for (int ch = 0; ch < 3; ++ch)
                    out[(((size_t)bb * 3 + ch) * HH + oy) * WW + ox] = o[sg][ch];
            }
        }
    }
}

extern "C" void kernel_launch(void* const* d_in, const int* in_sizes, int n_in,
                              void* d_out, int out_size, void* d_ws, size_t ws_size,
                              hipStream_t stream) {
    const float* sharp = (const float*)d_in[0];
    const float* coc   = (const float*)d_in[1];
    float* outp        = (float*)d_out;
    dim3 grid(WW / TW, HH / TH, NB);
    defocus_kernel<<<grid, dim3(256), 0, stream>>>(sharp, coc, outp);
}